// Round 6
// baseline (1665.890 us; speedup 1.0000x reference)
//
#include <hip/hip_runtime.h>
#include <hip/hip_bf16.h>

#define BB 4
#define MM 50000
#define FINF 128
#define FOUTF 128
#define KCH 4
#define EE 800000
#define NROWS (BB*MM)      // 200000
#define XC 512             // columns of X = B*FIN
#define CD 512             // reduction dim = FIN*K
#define SCB 512            // counts per scan block
#define NSB ((MM + SCB - 1)/SCB)   // 98
#define GXB ((MM + 255)/256)       // 196 row-blocks per batch in gemm
#define NSS 16             // column sub-slabs for XCD-pinned spmm (64 B/row each)
#define RPB 16             // rows per spmm block (16 waves x 1024 thr)
#define RBS (MM/RPB)       // 3125 row-blocks per sub-slab

__device__ __forceinline__ float bf2f(unsigned short u){
    union{unsigned int i; float f;} v; v.i = ((unsigned int)u) << 16; return v.f;
}
__device__ __forceinline__ unsigned short f2bf(float f){
    union{float f; unsigned int i;} v; v.f = f;
    unsigned int r = v.i + 0x7FFF + ((v.i >> 16) & 1);   // RNE
    return (unsigned short)(r >> 16);
}

typedef __bf16 bf16x8 __attribute__((ext_vector_type(8)));
typedef float  f32x4  __attribute__((ext_vector_type(4)));

typedef __attribute__((address_space(3))) unsigned int       lds_uint;
typedef const __attribute__((address_space(1))) unsigned int gbl_uint;

// ---- X0[m][b*128+f] = bf16(x[b][m][f]) ----
__global__ __launch_bounds__(256) void k_init_x0(const float* __restrict__ x,
                                                 unsigned short* __restrict__ X0){
    int tid = blockIdx.x*256 + threadIdx.x;          // one float4 each
    if (tid >= BB*MM*FINF/4) return;
    int f4 = tid & 31;
    int t  = tid >> 5;                               // b*MM + m
    int m  = t % MM, b = t / MM;
    float4 v = ((const float4*)x)[tid];
    ushort4 o;
    o.x = f2bf(v.x); o.y = f2bf(v.y); o.z = f2bf(v.z); o.w = f2bf(v.w);
    *(ushort4*)(X0 + (size_t)m*XC + b*FINF + f4*4) = o;
}

// ---- Wt swizzled into MFMA B-fragment order ----
__global__ __launch_bounds__(256) void k_prepw(const float* __restrict__ kern,
                                               unsigned short* __restrict__ Wt){
    int tid = blockIdx.x*256 + threadIdx.x;          // 65536
    int c = tid & 511, n = tid >> 9;
    int kc = c >> 7, f = c & 127;
    int ns = n >> 4, l16 = n & 15;
    int ks = c >> 5, rem = c & 31, g = rem >> 3, j = rem & 7;
    int lane = g*16 + l16;
    Wt[((ns*16 + ks)*64 + lane)*8 + j] = f2bf(kern[(f*KCH + kc)*FOUTF + n]);
}

// ---- CSR build ----
__global__ __launch_bounds__(256) void k_hist(const int* __restrict__ rows, int* __restrict__ counts){
    int e = blockIdx.x*256 + threadIdx.x;
    if (e < EE) atomicAdd(&counts[rows[e]], 1);
}

// parallel scan, 3 stages
__global__ __launch_bounds__(256) void k_scanA(const int* __restrict__ counts, int* __restrict__ part){
    __shared__ int red[256];
    int b = blockIdx.x, t = threadIdx.x;
    int i = b*SCB + t;
    int s = 0;
    if (i < MM) s += counts[i];
    if (i + 256 < (b+1)*SCB && i + 256 < MM) s += counts[i+256];
    red[t] = s; __syncthreads();
    for (int d = 128; d > 0; d >>= 1){
        if (t < d) red[t] += red[t+d];
        __syncthreads();
    }
    if (t == 0) part[b] = red[0];
}

__global__ __launch_bounds__(128) void k_scanB(int* __restrict__ part){
    __shared__ int sh[128];
    int t = threadIdx.x;
    sh[t] = (t < NSB) ? part[t] : 0;
    __syncthreads();
    for (int d = 1; d < 128; d <<= 1){
        int v = (t >= d) ? sh[t-d] : 0;
        __syncthreads();
        sh[t] += v;
        __syncthreads();
    }
    if (t < NSB) part[t] = sh[t];                    // inclusive sums
}

__global__ __launch_bounds__(256) void k_scanC(const int* __restrict__ counts, const int* __restrict__ part,
                                               int* __restrict__ offs, int* __restrict__ cursor){
    __shared__ int sh[256];
    int b = blockIdx.x, t = threadIdx.x;
    int base = (b == 0) ? 0 : part[b-1];
    int i0 = b*SCB + 2*t;
    int c0 = (i0     < MM) ? counts[i0]   : 0;
    int c1 = (i0 + 1 < MM) ? counts[i0+1] : 0;
    sh[t] = c0 + c1; __syncthreads();
    for (int d = 1; d < 256; d <<= 1){
        int v = (t >= d) ? sh[t-d] : 0;
        __syncthreads();
        sh[t] += v;
        __syncthreads();
    }
    int excl = base + sh[t] - (c0 + c1);
    if (i0 < MM){ offs[i0] = excl;      cursor[i0] = excl; }
    if (i0 + 1 < MM){ offs[i0+1] = excl + c0; cursor[i0+1] = excl + c0; }
    if (b == gridDim.x-1 && t == 255) offs[MM] = EE;
}

// edges stored as (col*1024 byte offset, bits(val)) — pre-shifted to cut spmm VALU
__global__ __launch_bounds__(256) void k_scatter(const int* __restrict__ rows, const int* __restrict__ cols,
                                                 const float* __restrict__ vals, int* __restrict__ cursor,
                                                 int2* __restrict__ edges){
    int e = blockIdx.x*256 + threadIdx.x;
    if (e >= EE) return;
    int r = rows[e];
    int pos = atomicAdd(&cursor[r], 1);
    edges[pos] = make_int2(cols[e] << 10, __float_as_int(vals[e]));
}

// ---- XCD-pinned sub-slab SpMM: Xout = alpha*(L@Xin) - (sub?Xprev:0) ----
// 16 column sub-slabs of 64 B/row; working set per sub-slab = 3.2 MB < 4 MB L2.
// blockIdx%8 -> XCD (round-robin dispatch): XCD x handles sub-slabs x, x+8 only,
// so all gather re-reads are XCD-local L2 hits, and pass N+1 re-reads the lines
// pass N wrote on the SAME XCD. Edge stream is non-temporal (no L2 pollution).
// Lane layout: 4 x 16-lane groups; group qg processes edge j+qg, each lane 4 B
// (one 64-B line per group). Partials combined by shfl_xor(16,32) at the end.
// GRID MUST BE NSS*RBS = 50000 (R5 crash: a wrong grid expression launched
// 200000 blocks -> m up to ~350K -> OOB writes over the workspace).
__global__ __launch_bounds__(1024) void k_spmm_x(const unsigned short* __restrict__ Xin,
                                                 const unsigned short* __restrict__ Xprev,
                                                 unsigned short* __restrict__ Xout,
                                                 const int* __restrict__ offs,
                                                 const int2* __restrict__ edges,
                                                 float alpha, int sub){
    const int i    = blockIdx.x;                     // 0..49999
    const int xcd  = i & 7;
    const int j2   = i >> 3;                         // 0..6249
    const int half = (j2 >= RBS) ? 1 : 0;
    const int ss   = xcd + (half << 3);              // sub-slab 0..15
    const int rb   = j2 - half*RBS;
    const int wave = threadIdx.x >> 6;               // 0..15
    const int m    = rb*RPB + wave;                  // row 0..49999
    const int lane = threadIdx.x & 63;
    const int qg   = lane >> 4;                      // edge-slot 0..3
    const int cl   = lane & 15;
    const int cb   = ss*64 + cl*4;                   // byte offset within 1024-B row

    const int start = offs[m], end = offs[m+1];
    float a0 = 0.f, a1 = 0.f;
    const char* __restrict__ bp = (const char*)Xin;
    const long long* __restrict__ ep = (const long long*)edges;
    for (int j = start; j < end; j += 8){
        #pragma unroll
        for (int q = 0; q < 2; ++q){
            int je = j + q*4 + qg;
            bool ok = je < end;
            long long ev = __builtin_nontemporal_load(ep + (ok ? je : 0));
            float val = ok ? __int_as_float((int)(ev >> 32)) : 0.f;
            unsigned int xv = *(const unsigned int*)(bp + (unsigned)(int)ev + cb);
            union{unsigned int u; float f;} lo, hi;
            lo.u = xv << 16; hi.u = xv & 0xffff0000u;
            a0 += val*lo.f; a1 += val*hi.f;
        }
    }
    a0 += __shfl_xor(a0, 16); a0 += __shfl_xor(a0, 32);
    a1 += __shfl_xor(a1, 16); a1 += __shfl_xor(a1, 32);
    a0 *= alpha; a1 *= alpha;
    size_t ob = (size_t)m*1024 + cb;
    if (sub){
        unsigned int pv = *(const unsigned int*)((const char*)Xprev + ob);
        union{unsigned int u; float f;} lo, hi;
        lo.u = pv << 16; hi.u = pv & 0xffff0000u;
        a0 -= lo.f; a1 -= hi.f;
    }
    if (qg == 0){
        unsigned int o = ((unsigned int)f2bf(a1) << 16) | (unsigned int)f2bf(a0);
        *(unsigned int*)((char*)Xout + ob) = o;
    }
}

// ---- GEMM: 256 rows x 128 cols per block, A+B staged via global_load_lds
// double-buffered LDS (BK=32, 16 k-steps). A-tile LDS uses XOR swizzle
// byte ^= ((row&6)<<3) applied on BOTH staging source and ds_read (G21). ----
__global__ __launch_bounds__(256, 2) void k_gemm(const unsigned short* __restrict__ X0,
                                                 const unsigned short* __restrict__ X1,
                                                 const unsigned short* __restrict__ X2,
                                                 const unsigned short* __restrict__ X3,
                                                 const unsigned short* __restrict__ Wt,
                                                 float* __restrict__ Y,
                                                 float* __restrict__ Ypart){
    const int wave = threadIdx.x >> 6;
    const int lane = threadIdx.x & 63;
    const int l16  = lane & 15;
    const int g    = lane >> 4;                       // 0..3
    const int bidx = blockIdx.y;                      // batch
    const int m0   = blockIdx.x*256;                  // row-tile base

    __shared__ unsigned short As[2][8192];            // 2 x 16 KB: 256 rows x 32 k (swizzled)
    __shared__ unsigned short Bs[2][4096];            // 2 x 8 KB: 128 cols x 32 k (frag order)

    const unsigned short* const Xs[4] = {X0, X1, X2, X3};

    f32x4 acc[4][8];
    #pragma unroll
    for (int i = 0; i < 4; ++i)
        #pragma unroll
        for (int j = 0; j < 8; ++j) acc[i][j] = (f32x4){0.f,0.f,0.f,0.f};

    auto stage = [&](int buf, int ks){
        const unsigned short* Xb = Xs[ks >> 2];
        const int f0 = (ks & 3)*64;                   // byte offset of 32-k slice in 256-B batch row
        #pragma unroll
        for (int q = 0; q < 4; ++q){                  // A: 16 KB
            int row = q*64 + wave*16 + (lane >> 2);
            int mr  = m0 + row; if (mr >= MM) mr = MM-1;
            int inner = ((lane & 3)*16) ^ ((row & 6) << 3);   // source pre-swizzle
            const char* src = (const char*)Xb + (size_t)mr*1024 + bidx*256 + f0 + inner;
            lds_uint* dst = (lds_uint*)(&As[buf][(q*4096 + wave*1024)/2]);
            __builtin_amdgcn_global_load_lds((gbl_uint*)src, dst, 16, 0, 0);
        }
        #pragma unroll
        for (int q = 0; q < 2; ++q){                  // B: 8 KB
            int ns = q*4 + wave;
            const char* src = (const char*)Wt + (size_t)(ns*16 + ks)*1024 + lane*16;
            lds_uint* dst = (lds_uint*)(&Bs[buf][ns*512]);
            __builtin_amdgcn_global_load_lds((gbl_uint*)src, dst, 16, 0, 0);
        }
    };

    stage(0, 0);
    __syncthreads();

    for (int ks = 0; ks < 16; ++ks){
        const int buf = ks & 1;
        if (ks < 15) stage(buf ^ 1, ks + 1);

        bf16x8 a[4];
        #pragma unroll
        for (int i = 0; i < 4; ++i){
            int rr = wave*64 + i*16 + l16;
            int phys = rr*64 + ((g*16) ^ ((rr & 6) << 3));    // matching read swizzle
            a[i] = *(const bf16x8*)((const char*)&As[buf][0] + phys);
        }
        #pragma unroll
        for (int ns = 0; ns < 8; ++ns){
            bf16x8 b = *(const bf16x8*)(&Bs[buf][ns*512 + lane*8]);
            #pragma unroll
            for (int i = 0; i < 4; ++i)
                acc[i][ns] = __builtin_amdgcn_mfma_f32_16x16x32_bf16(a[i], b, acc[i][ns], 0, 0, 0);
        }
        __syncthreads();
    }

    // epilogue: relu + store + per-block column partial sums
    __shared__ float ldsum[4][FOUTF];
    float csum[8];
    #pragma unroll
    for (int ns = 0; ns < 8; ++ns) csum[ns] = 0.f;

    #pragma unroll
    for (int i = 0; i < 4; ++i){
        #pragma unroll
        for (int reg = 0; reg < 4; ++reg){
            int mr = m0 + wave*64 + i*16 + g*4 + reg;
            if (mr < MM){
                #pragma unroll
                for (int ns = 0; ns < 8; ++ns){
                    float v = acc[i][ns][reg];
                    v = v > 0.f ? v : 0.f;
                    Y[((size_t)bidx*MM + mr)*FOUTF + ns*16 + l16] = v;
                    csum[ns] += v;
                }
            }
        }
    }
    #pragma unroll
    for (int ns = 0; ns < 8; ++ns){
        float v = csum[ns];
        v += __shfl_xor(v, 16);                       // sum over g = 0..3
        v += __shfl_xor(v, 32);
        csum[ns] = v;
    }
    if (lane < 16){
        #pragma unroll
        for (int ns = 0; ns < 8; ++ns) ldsum[wave][ns*16 + lane] = csum[ns];
    }
    __syncthreads();
    int t = threadIdx.x;
    if (t < FOUTF){
        float s = ldsum[0][t] + ldsum[1][t] + ldsum[2][t] + ldsum[3][t];
        Ypart[((size_t)bidx*GXB + blockIdx.x)*FOUTF + t] = s;
    }
}

// ---- SE MLP: reduce gemm partials -> mean -> u = sigmoid(swish(mean@Wd+bd)@Wu+bu) ----
__global__ __launch_bounds__(128) void k_se(const float* __restrict__ Ypart,
                                            const float* __restrict__ Wd, const float* __restrict__ bd,
                                            const float* __restrict__ Wu, const float* __restrict__ bu,
                                            float* __restrict__ u){
    int b = blockIdx.x, t = threadIdx.x;
    __shared__ float sm[128];
    __shared__ float dsh[16];
    float s = 0.f;
    for (int j = 0; j < GXB; ++j) s += Ypart[((size_t)b*GXB + j)*FOUTF + t];
    sm[t] = s * (1.0f/MM);
    __syncthreads();
    if (t < 16){
        float a = bd[t];
        for (int f = 0; f < 128; ++f) a += sm[f]*Wd[f*16 + t];
        dsh[t] = a / (1.f + expf(-a));                // swish
    }
    __syncthreads();
    float a = bu[t];
    for (int j = 0; j < 16; ++j) a += dsh[j]*Wu[j*FOUTF + t];
    u[b*FOUTF + t] = 1.f/(1.f + expf(-a));
}

// ---- out = Y * u[b] ----
__global__ __launch_bounds__(256) void k_scale(const float* __restrict__ Y, const float* __restrict__ u,
                                               float* __restrict__ out){
    int tid = blockIdx.x*256 + threadIdx.x;
    if (tid >= NROWS*FOUTF/4) return;
    int b  = tid / (MM*FOUTF/4);
    int f4 = tid & 31;
    float4 yv = ((const float4*)Y)[tid];
    float4 uv = *(const float4*)(u + b*FOUTF + f4*4);
    float4 o;
    o.x = yv.x*uv.x; o.y = yv.y*uv.y; o.z = yv.z*uv.z; o.w = yv.w*uv.w;
    ((float4*)out)[tid] = o;
}

extern "C" void kernel_launch(void* const* d_in, const int* in_sizes, int n_in,
                              void* d_out, int out_size, void* d_ws, size_t ws_size,
                              hipStream_t stream){
    (void)in_sizes; (void)n_in; (void)out_size; (void)ws_size;
    const float* x    = (const float*)d_in[0];
    const float* lv   = (const float*)d_in[1];
    const int*   lr   = (const int*)d_in[2];
    const int*   lc   = (const int*)d_in[3];
    const float* kern = (const float*)d_in[4];
    const float* Wd   = (const float*)d_in[5];
    const float* bd   = (const float*)d_in[6];
    const float* Wu   = (const float*)d_in[7];
    const float* bu   = (const float*)d_in[8];
    float* out = (float*)d_out;

    char* w = (char*)d_ws;
    size_t off = 0;
    auto take = [&](size_t bytes)->char*{
        char* p = w + off; off += (bytes + 255) & ~(size_t)255; return p;
    };
    unsigned short* X[4];
    for (int i = 0; i < 4; ++i) X[i] = (unsigned short*)take((size_t)MM*XC*2);
    float* Y           = (float*)take((size_t)NROWS*FOUTF*4);
    unsigned short* Wt = (unsigned short*)take((size_t)FOUTF*CD*2);
    int* counts        = (int*)take((size_t)MM*4);
    int* offs          = (int*)take((size_t)(MM+1)*4);
    int* cursor        = (int*)take((size_t)MM*4);
    int2* edges        = (int2*)take((size_t)EE*8);
    int* part          = (int*)take((size_t)NSB*4);
    float* Ypart       = (float*)take((size_t)BB*GXB*FOUTF*4);
    float* u           = (float*)take((size_t)BB*FOUTF*4);

    hipMemsetAsync(counts, 0, MM*4, stream);

    k_init_x0<<<25000, 256, 0, stream>>>(x, X[0]);
    k_prepw<<<256, 256, 0, stream>>>(kern, Wt);
    k_hist<<<(EE+255)/256, 256, 0, stream>>>(lr, counts);
    k_scanA<<<NSB, 256, 0, stream>>>(counts, part);
    k_scanB<<<1, 128, 0, stream>>>(part);
    k_scanC<<<NSB, 256, 0, stream>>>(counts, part, offs, cursor);
    k_scatter<<<(EE+255)/256, 256, 0, stream>>>(lr, lc, lv, cursor, edges);

    // Chebyshev recurrence, XCD-pinned sub-slab passes (grid = NSS*RBS = 50000)
    k_spmm_x<<<NSS*RBS, 1024, 0, stream>>>(X[0], X[0], X[1], offs, edges, 1.0f, 0);
    k_spmm_x<<<NSS*RBS, 1024, 0, stream>>>(X[1], X[0], X[2], offs, edges, 2.0f, 1);
    k_spmm_x<<<NSS*RBS, 1024, 0, stream>>>(X[2], X[1], X[3], offs, edges, 2.0f, 1);

    dim3 ggemm(GXB, BB);
    k_gemm<<<ggemm, 256, 0, stream>>>(X[0], X[1], X[2], X[3], Wt, Y, Ypart);

    k_se<<<BB, 128, 0, stream>>>(Ypart, Wd, bd, Wu, bu, u);
    k_scale<<<25000, 256, 0, stream>>>(Y, u, out);
}

// Round 8
// 1279.332 us; speedup vs baseline: 1.3022x; 1.3022x over previous
//
#include <hip/hip_runtime.h>
#include <hip/hip_bf16.h>

#define BB 4
#define MM 50000
#define FINF 128
#define FOUTF 128
#define KCH 4
#define EE 800000
#define NROWS (BB*MM)      // 200000
#define XC 512             // columns of X = B*FIN
#define CD 512             // reduction dim = FIN*K
#define SCB 512            // counts per scan block
#define NSB ((MM + SCB - 1)/SCB)   // 98
#define GXB ((MM + 255)/256)       // 196 row-blocks per batch in gemm
#define NSS 16             // column sub-slabs for XCD-pinned spmm (64 B/row each)
#define RPB 16             // rows per spmm block (16 waves x 1024 thr)
#define RBS (MM/RPB)       // 3125 row-blocks per sub-slab

__device__ __forceinline__ float bf2f(unsigned short u){
    union{unsigned int i; float f;} v; v.i = ((unsigned int)u) << 16; return v.f;
}
__device__ __forceinline__ unsigned short f2bf(float f){
    union{float f; unsigned int i;} v; v.f = f;
    unsigned int r = v.i + 0x7FFF + ((v.i >> 16) & 1);   // RNE
    return (unsigned short)(r >> 16);
}

typedef __bf16 bf16x8 __attribute__((ext_vector_type(8)));
typedef float  f32x4  __attribute__((ext_vector_type(4)));

typedef __attribute__((address_space(3))) unsigned int       lds_uint;
typedef const __attribute__((address_space(1))) unsigned int gbl_uint;

// ---- X0[m][b*128+f] = bf16(x[b][m][f]) ----
__global__ __launch_bounds__(256) void k_init_x0(const float* __restrict__ x,
                                                 unsigned short* __restrict__ X0){
    int tid = blockIdx.x*256 + threadIdx.x;          // one float4 each
    if (tid >= BB*MM*FINF/4) return;
    int f4 = tid & 31;
    int t  = tid >> 5;                               // b*MM + m
    int m  = t % MM, b = t / MM;
    float4 v = ((const float4*)x)[tid];
    ushort4 o;
    o.x = f2bf(v.x); o.y = f2bf(v.y); o.z = f2bf(v.z); o.w = f2bf(v.w);
    *(ushort4*)(X0 + (size_t)m*XC + b*FINF + f4*4) = o;
}

// ---- Wt swizzled into MFMA B-fragment order ----
__global__ __launch_bounds__(256) void k_prepw(const float* __restrict__ kern,
                                               unsigned short* __restrict__ Wt){
    int tid = blockIdx.x*256 + threadIdx.x;          // 65536
    int c = tid & 511, n = tid >> 9;
    int kc = c >> 7, f = c & 127;
    int ns = n >> 4, l16 = n & 15;
    int ks = c >> 5, rem = c & 31, g = rem >> 3, j = rem & 7;
    int lane = g*16 + l16;
    Wt[((ns*16 + ks)*64 + lane)*8 + j] = f2bf(kern[(f*KCH + kc)*FOUTF + n]);
}

// ---- CSR build ----
__global__ __launch_bounds__(256) void k_hist(const int* __restrict__ rows, int* __restrict__ counts){
    int e = blockIdx.x*256 + threadIdx.x;
    if (e < EE) atomicAdd(&counts[rows[e]], 1);
}

// parallel scan, 3 stages
__global__ __launch_bounds__(256) void k_scanA(const int* __restrict__ counts, int* __restrict__ part){
    __shared__ int red[256];
    int b = blockIdx.x, t = threadIdx.x;
    int i = b*SCB + t;
    int s = 0;
    if (i < MM) s += counts[i];
    if (i + 256 < (b+1)*SCB && i + 256 < MM) s += counts[i+256];
    red[t] = s; __syncthreads();
    for (int d = 128; d > 0; d >>= 1){
        if (t < d) red[t] += red[t+d];
        __syncthreads();
    }
    if (t == 0) part[b] = red[0];
}

__global__ __launch_bounds__(128) void k_scanB(int* __restrict__ part){
    __shared__ int sh[128];
    int t = threadIdx.x;
    sh[t] = (t < NSB) ? part[t] : 0;
    __syncthreads();
    for (int d = 1; d < 128; d <<= 1){
        int v = (t >= d) ? sh[t-d] : 0;
        __syncthreads();
        sh[t] += v;
        __syncthreads();
    }
    if (t < NSB) part[t] = sh[t];                    // inclusive sums
}

__global__ __launch_bounds__(256) void k_scanC(const int* __restrict__ counts, const int* __restrict__ part,
                                               int* __restrict__ offs, int* __restrict__ cursor){
    __shared__ int sh[256];
    int b = blockIdx.x, t = threadIdx.x;
    int base = (b == 0) ? 0 : part[b-1];
    int i0 = b*SCB + 2*t;
    int c0 = (i0     < MM) ? counts[i0]   : 0;
    int c1 = (i0 + 1 < MM) ? counts[i0+1] : 0;
    sh[t] = c0 + c1; __syncthreads();
    for (int d = 1; d < 256; d <<= 1){
        int v = (t >= d) ? sh[t-d] : 0;
        __syncthreads();
        sh[t] += v;
        __syncthreads();
    }
    int excl = base + sh[t] - (c0 + c1);
    if (i0 < MM){ offs[i0] = excl;      cursor[i0] = excl; }
    if (i0 + 1 < MM){ offs[i0+1] = excl + c0; cursor[i0+1] = excl + c0; }
    if (b == gridDim.x-1 && t == 255) offs[MM] = EE;
}

// edges stored as (col*1024 byte offset, bits(val)) — pre-shifted to cut spmm VALU
__global__ __launch_bounds__(256) void k_scatter(const int* __restrict__ rows, const int* __restrict__ cols,
                                                 const float* __restrict__ vals, int* __restrict__ cursor,
                                                 int2* __restrict__ edges){
    int e = blockIdx.x*256 + threadIdx.x;
    if (e >= EE) return;
    int r = rows[e];
    int pos = atomicAdd(&cursor[r], 1);
    edges[pos] = make_int2(cols[e] << 10, __float_as_int(vals[e]));
}

// ---- XCD-pinned sub-slab SpMM: Xout = alpha*(L@Xin) - (sub?Xprev:0) ----
// 16 column sub-slabs of 64 B/row; working set per sub-slab = 3.2 MB < 4 MB L2.
// blockIdx%8 -> XCD (round-robin dispatch): XCD x handles sub-slabs x, x+8.
// R6 lesson: edge loads MUST be normal cached loads (edges = 6.4 MB, re-read
// 16x -> L2/L3 hits). R6's nontemporal edge loads forced ~900-cy fabric stalls
// on the critical path of a ~2-iteration loop (455 us/pass, FETCH 513 MB).
// Here edges are prefetched one burst ahead so gathers never wait on them.
// Lane layout: 4 x 16-lane groups; group qg handles edges j+qg and j+4+qg,
// each lane 4 B (one 64-B line per group). Partials combined via shfl_xor.
// GRID MUST BE NSS*RBS = 50000.
__global__ __launch_bounds__(1024) void k_spmm_x(const unsigned short* __restrict__ Xin,
                                                 const unsigned short* __restrict__ Xprev,
                                                 unsigned short* __restrict__ Xout,
                                                 const int* __restrict__ offs,
                                                 const int2* __restrict__ edges,
                                                 float alpha, int sub){
    const int i    = blockIdx.x;                     // 0..49999
    const int xcd  = i & 7;
    const int j2   = i >> 3;                         // 0..6249
    const int half = (j2 >= RBS) ? 1 : 0;
    const int ss   = xcd + (half << 3);              // sub-slab 0..15
    const int rb   = j2 - half*RBS;
    const int wave = threadIdx.x >> 6;               // 0..15
    const int m    = rb*RPB + wave;                  // row 0..49999
    const int lane = threadIdx.x & 63;
    const int qg   = lane >> 4;                      // edge-slot 0..3
    const int cl   = lane & 15;
    const int cb   = ss*64 + cl*4;                   // byte offset within 1024-B row

    const int start = offs[m], end = offs[m+1];
    float a0 = 0.f, a1 = 0.f;
    const char* __restrict__ bp = (const char*)Xin;
    const long long* __restrict__ ep = (const long long*)edges;

    int j = start;
    int  i0 = j + qg,  i1 = j + 4 + qg;
    bool ok0 = i0 < end, ok1 = i1 < end;
    long long ev0 = ep[ok0 ? i0 : 0];                // ep[0] always valid
    long long ev1 = ep[ok1 ? i1 : 0];
    while (j < end){
        const long long c0 = ev0, c1 = ev1;
        const bool k0 = ok0, k1 = ok1;
        j += 8;
        if (j < end){                                // prefetch next burst (cached)
            i0 = j + qg; i1 = j + 4 + qg;
            ok0 = i0 < end; ok1 = i1 < end;
            ev0 = ep[ok0 ? i0 : 0];
            ev1 = ep[ok1 ? i1 : 0];
        }
        unsigned int xv0 = *(const unsigned int*)(bp + (unsigned)(int)c0 + cb);
        unsigned int xv1 = *(const unsigned int*)(bp + (unsigned)(int)c1 + cb);
        float v0 = k0 ? __int_as_float((int)(c0 >> 32)) : 0.f;
        float v1 = k1 ? __int_as_float((int)(c1 >> 32)) : 0.f;
        union{unsigned int u; float f;} l0, h0, l1, h1;
        l0.u = xv0 << 16; h0.u = xv0 & 0xffff0000u;
        l1.u = xv1 << 16; h1.u = xv1 & 0xffff0000u;
        a0 += v0*l0.f; a1 += v0*h0.f;
        a0 += v1*l1.f; a1 += v1*h1.f;
    }
    a0 += __shfl_xor(a0, 16); a0 += __shfl_xor(a0, 32);
    a1 += __shfl_xor(a1, 16); a1 += __shfl_xor(a1, 32);
    a0 *= alpha; a1 *= alpha;
    size_t ob = (size_t)m*1024 + cb;
    if (sub){
        unsigned int pv = *(const unsigned int*)((const char*)Xprev + ob);
        union{unsigned int u; float f;} lo, hi;
        lo.u = pv << 16; hi.u = pv & 0xffff0000u;
        a0 -= lo.f; a1 -= hi.f;
    }
    if (qg == 0){
        unsigned int o = ((unsigned int)f2bf(a1) << 16) | (unsigned int)f2bf(a0);
        *(unsigned int*)((char*)Xout + ob) = o;
    }
}

// ---- GEMM: 256 rows x 128 cols per block, A+B staged via global_load_lds
// double-buffered LDS (BK=32, 16 k-steps). A-tile LDS uses XOR swizzle
// byte ^= ((row&6)<<3) applied on BOTH staging source and ds_read (G21). ----
__global__ __launch_bounds__(256, 2) void k_gemm(const unsigned short* __restrict__ X0,
                                                 const unsigned short* __restrict__ X1,
                                                 const unsigned short* __restrict__ X2,
                                                 const unsigned short* __restrict__ X3,
                                                 const unsigned short* __restrict__ Wt,
                                                 float* __restrict__ Y,
                                                 float* __restrict__ Ypart){
    const int wave = threadIdx.x >> 6;
    const int lane = threadIdx.x & 63;
    const int l16  = lane & 15;
    const int g    = lane >> 4;                       // 0..3
    const int bidx = blockIdx.y;                      // batch
    const int m0   = blockIdx.x*256;                  // row-tile base

    __shared__ unsigned short As[2][8192];            // 2 x 16 KB: 256 rows x 32 k (swizzled)
    __shared__ unsigned short Bs[2][4096];            // 2 x 8 KB: 128 cols x 32 k (frag order)

    const unsigned short* const Xs[4] = {X0, X1, X2, X3};

    f32x4 acc[4][8];
    #pragma unroll
    for (int i = 0; i < 4; ++i)
        #pragma unroll
        for (int j = 0; j < 8; ++j) acc[i][j] = (f32x4){0.f,0.f,0.f,0.f};

    auto stage = [&](int buf, int ks){
        const unsigned short* Xb = Xs[ks >> 2];
        const int f0 = (ks & 3)*64;                   // byte offset of 32-k slice in 256-B batch row
        #pragma unroll
        for (int q = 0; q < 4; ++q){                  // A: 16 KB
            int row = q*64 + wave*16 + (lane >> 2);
            int mr  = m0 + row; if (mr >= MM) mr = MM-1;
            int inner = ((lane & 3)*16) ^ ((row & 6) << 3);   // source pre-swizzle
            const char* src = (const char*)Xb + (size_t)mr*1024 + bidx*256 + f0 + inner;
            lds_uint* dst = (lds_uint*)(&As[buf][(q*4096 + wave*1024)/2]);
            __builtin_amdgcn_global_load_lds((gbl_uint*)src, dst, 16, 0, 0);
        }
        #pragma unroll
        for (int q = 0; q < 2; ++q){                  // B: 8 KB
            int ns = q*4 + wave;
            const char* src = (const char*)Wt + (size_t)(ns*16 + ks)*1024 + lane*16;
            lds_uint* dst = (lds_uint*)(&Bs[buf][ns*512]);
            __builtin_amdgcn_global_load_lds((gbl_uint*)src, dst, 16, 0, 0);
        }
    };

    stage(0, 0);
    __syncthreads();

    for (int ks = 0; ks < 16; ++ks){
        const int buf = ks & 1;
        if (ks < 15) stage(buf ^ 1, ks + 1);

        bf16x8 a[4];
        #pragma unroll
        for (int i = 0; i < 4; ++i){
            int rr = wave*64 + i*16 + l16;
            int phys = rr*64 + ((g*16) ^ ((rr & 6) << 3));    // matching read swizzle
            a[i] = *(const bf16x8*)((const char*)&As[buf][0] + phys);
        }
        #pragma unroll
        for (int ns = 0; ns < 8; ++ns){
            bf16x8 b = *(const bf16x8*)(&Bs[buf][ns*512 + lane*8]);
            #pragma unroll
            for (int i = 0; i < 4; ++i)
                acc[i][ns] = __builtin_amdgcn_mfma_f32_16x16x32_bf16(a[i], b, acc[i][ns], 0, 0, 0);
        }
        __syncthreads();
    }

    // epilogue: relu + store + per-block column partial sums
    __shared__ float ldsum[4][FOUTF];
    float csum[8];
    #pragma unroll
    for (int ns = 0; ns < 8; ++ns) csum[ns] = 0.f;

    #pragma unroll
    for (int i = 0; i < 4; ++i){
        #pragma unroll
        for (int reg = 0; reg < 4; ++reg){
            int mr = m0 + wave*64 + i*16 + g*4 + reg;
            if (mr < MM){
                #pragma unroll
                for (int ns = 0; ns < 8; ++ns){
                    float v = acc[i][ns][reg];
                    v = v > 0.f ? v : 0.f;
                    Y[((size_t)bidx*MM + mr)*FOUTF + ns*16 + l16] = v;
                    csum[ns] += v;
                }
            }
        }
    }
    #pragma unroll
    for (int ns = 0; ns < 8; ++ns){
        float v = csum[ns];
        v += __shfl_xor(v, 16);                       // sum over g = 0..3
        v += __shfl_xor(v, 32);
        csum[ns] = v;
    }
    if (lane < 16){
        #pragma unroll
        for (int ns = 0; ns < 8; ++ns) ldsum[wave][ns*16 + lane] = csum[ns];
    }
    __syncthreads();
    int t = threadIdx.x;
    if (t < FOUTF){
        float s = ldsum[0][t] + ldsum[1][t] + ldsum[2][t] + ldsum[3][t];
        Ypart[((size_t)bidx*GXB + blockIdx.x)*FOUTF + t] = s;
    }
}

// ---- SE MLP: reduce gemm partials -> mean -> u = sigmoid(swish(mean@Wd+bd)@Wu+bu) ----
__global__ __launch_bounds__(128) void k_se(const float* __restrict__ Ypart,
                                            const float* __restrict__ Wd, const float* __restrict__ bd,
                                            const float* __restrict__ Wu, const float* __restrict__ bu,
                                            float* __restrict__ u){
    int b = blockIdx.x, t = threadIdx.x;
    __shared__ float sm[128];
    __shared__ float dsh[16];
    float s = 0.f;
    for (int j = 0; j < GXB; ++j) s += Ypart[((size_t)b*GXB + j)*FOUTF + t];
    sm[t] = s * (1.0f/MM);
    __syncthreads();
    if (t < 16){
        float a = bd[t];
        for (int f = 0; f < 128; ++f) a += sm[f]*Wd[f*16 + t];
        dsh[t] = a / (1.f + expf(-a));                // swish
    }
    __syncthreads();
    float a = bu[t];
    for (int j = 0; j < 16; ++j) a += dsh[j]*Wu[j*FOUTF + t];
    u[b*FOUTF + t] = 1.f/(1.f + expf(-a));
}

// ---- out = Y * u[b] ----
__global__ __launch_bounds__(256) void k_scale(const float* __restrict__ Y, const float* __restrict__ u,
                                               float* __restrict__ out){
    int tid = blockIdx.x*256 + threadIdx.x;
    if (tid >= NROWS*FOUTF/4) return;
    int b  = tid / (MM*FOUTF/4);
    int f4 = tid & 31;
    float4 yv = ((const float4*)Y)[tid];
    float4 uv = *(const float4*)(u + b*FOUTF + f4*4);
    float4 o;
    o.x = yv.x*uv.x; o.y = yv.y*uv.y; o.z = yv.z*uv.z; o.w = yv.w*uv.w;
    ((float4*)out)[tid] = o;
}

extern "C" void kernel_launch(void* const* d_in, const int* in_sizes, int n_in,
                              void* d_out, int out_size, void* d_ws, size_t ws_size,
                              hipStream_t stream){
    (void)in_sizes; (void)n_in; (void)out_size; (void)ws_size;
    const float* x    = (const float*)d_in[0];
    const float* lv   = (const float*)d_in[1];
    const int*   lr   = (const int*)d_in[2];
    const int*   lc   = (const int*)d_in[3];
    const float* kern = (const float*)d_in[4];
    const float* Wd   = (const float*)d_in[5];
    const float* bd   = (const float*)d_in[6];
    const float* Wu   = (const float*)d_in[7];
    const float* bu   = (const float*)d_in[8];
    float* out = (float*)d_out;

    char* w = (char*)d_ws;
    size_t off = 0;
    auto take = [&](size_t bytes)->char*{
        char* p = w + off; off += (bytes + 255) & ~(size_t)255; return p;
    };
    unsigned short* X[4];
    for (int i = 0; i < 4; ++i) X[i] = (unsigned short*)take((size_t)MM*XC*2);
    float* Y           = (float*)take((size_t)NROWS*FOUTF*4);
    unsigned short* Wt = (unsigned short*)take((size_t)FOUTF*CD*2);
    int* counts        = (int*)take((size_t)MM*4);
    int* offs          = (int*)take((size_t)(MM+1)*4);
    int* cursor        = (int*)take((size_t)MM*4);
    int2* edges        = (int2*)take((size_t)EE*8);
    int* part          = (int*)take((size_t)NSB*4);
    float* Ypart       = (float*)take((size_t)BB*GXB*FOUTF*4);
    float* u           = (float*)take((size_t)BB*FOUTF*4);

    hipMemsetAsync(counts, 0, MM*4, stream);

    k_init_x0<<<25000, 256, 0, stream>>>(x, X[0]);
    k_prepw<<<256, 256, 0, stream>>>(kern, Wt);
    k_hist<<<(EE+255)/256, 256, 0, stream>>>(lr, counts);
    k_scanA<<<NSB, 256, 0, stream>>>(counts, part);
    k_scanB<<<1, 128, 0, stream>>>(part);
    k_scanC<<<NSB, 256, 0, stream>>>(counts, part, offs, cursor);
    k_scatter<<<(EE+255)/256, 256, 0, stream>>>(lr, lc, lv, cursor, edges);

    // Chebyshev recurrence, XCD-pinned sub-slab passes (grid = NSS*RBS = 50000)
    k_spmm_x<<<NSS*RBS, 1024, 0, stream>>>(X[0], X[0], X[1], offs, edges, 1.0f, 0);
    k_spmm_x<<<NSS*RBS, 1024, 0, stream>>>(X[1], X[0], X[2], offs, edges, 2.0f, 1);
    k_spmm_x<<<NSS*RBS, 1024, 0, stream>>>(X[2], X[1], X[3], offs, edges, 2.0f, 1);

    dim3 ggemm(GXB, BB);
    k_gemm<<<ggemm, 256, 0, stream>>>(X[0], X[1], X[2], X[3], Wt, Y, Ypart);

    k_se<<<BB, 128, 0, stream>>>(Ypart, Wd, bd, Wu, bu, u);
    k_scale<<<25000, 256, 0, stream>>>(Y, u, out);
}

// Round 9
// 748.681 us; speedup vs baseline: 2.2251x; 1.7088x over previous
//
#include <hip/hip_runtime.h>
#include <hip/hip_bf16.h>

#define BB 4
#define MM 50000
#define FINF 128
#define FOUTF 128
#define KCH 4
#define EE 800000
#define NROWS (BB*MM)      // 200000
#define XC 512             // columns of X = B*FIN
#define CD 512             // reduction dim = FIN*K
#define SCB 512            // counts per scan block
#define NSB ((MM + SCB - 1)/SCB)   // 98
#define GXB ((MM + 255)/256)       // 196 row-blocks per batch in gemm

__device__ __forceinline__ float bf2f(unsigned short u){
    union{unsigned int i; float f;} v; v.i = ((unsigned int)u) << 16; return v.f;
}
__device__ __forceinline__ unsigned short f2bf(float f){
    union{float f; unsigned int i;} v; v.f = f;
    unsigned int r = v.i + 0x7FFF + ((v.i >> 16) & 1);   // RNE
    return (unsigned short)(r >> 16);
}

typedef __bf16 bf16x8 __attribute__((ext_vector_type(8)));
typedef float  f32x4  __attribute__((ext_vector_type(4)));

typedef __attribute__((address_space(3))) unsigned int       lds_uint;
typedef const __attribute__((address_space(1))) unsigned int gbl_uint;

// ---- X0[m][b*128+f] = bf16(x[b][m][f]) ----
__global__ __launch_bounds__(256) void k_init_x0(const float* __restrict__ x,
                                                 unsigned short* __restrict__ X0){
    int tid = blockIdx.x*256 + threadIdx.x;          // one float4 each
    if (tid >= BB*MM*FINF/4) return;
    int f4 = tid & 31;
    int t  = tid >> 5;                               // b*MM + m
    int m  = t % MM, b = t / MM;
    float4 v = ((const float4*)x)[tid];
    ushort4 o;
    o.x = f2bf(v.x); o.y = f2bf(v.y); o.z = f2bf(v.z); o.w = f2bf(v.w);
    *(ushort4*)(X0 + (size_t)m*XC + b*FINF + f4*4) = o;
}

// ---- Wt swizzled into MFMA B-fragment order ----
__global__ __launch_bounds__(256) void k_prepw(const float* __restrict__ kern,
                                               unsigned short* __restrict__ Wt){
    int tid = blockIdx.x*256 + threadIdx.x;          // 65536
    int c = tid & 511, n = tid >> 9;
    int kc = c >> 7, f = c & 127;
    int ns = n >> 4, l16 = n & 15;
    int ks = c >> 5, rem = c & 31, g = rem >> 3, j = rem & 7;
    int lane = g*16 + l16;
    Wt[((ns*16 + ks)*64 + lane)*8 + j] = f2bf(kern[(f*KCH + kc)*FOUTF + n]);
}

// ---- CSR build ----
__global__ __launch_bounds__(256) void k_hist(const int* __restrict__ rows, int* __restrict__ counts){
    int e = blockIdx.x*256 + threadIdx.x;
    if (e < EE) atomicAdd(&counts[rows[e]], 1);
}

// parallel scan, 2 stages (scanB folded into scanC)
__global__ __launch_bounds__(256) void k_scanA(const int* __restrict__ counts, int* __restrict__ part){
    __shared__ int red[256];
    int b = blockIdx.x, t = threadIdx.x;
    int i = b*SCB + t;
    int s = 0;
    if (i < MM) s += counts[i];
    if (i + 256 < (b+1)*SCB && i + 256 < MM) s += counts[i+256];
    red[t] = s; __syncthreads();
    for (int d = 128; d > 0; d >>= 1){
        if (t < d) red[t] += red[t+d];
        __syncthreads();
    }
    if (t == 0) part[b] = red[0];
}

__global__ __launch_bounds__(256) void k_scanC(const int* __restrict__ counts, const int* __restrict__ part,
                                               int* __restrict__ offs, int* __restrict__ cursor){
    __shared__ int sh[256];
    __shared__ int pp[NSB];
    int b = blockIdx.x, t = threadIdx.x;
    if (t < NSB) pp[t] = part[t];                    // raw per-block sums
    int i0 = b*SCB + 2*t;
    int c0 = (i0     < MM) ? counts[i0]   : 0;
    int c1 = (i0 + 1 < MM) ? counts[i0+1] : 0;
    sh[t] = c0 + c1; __syncthreads();
    int base = 0;
    for (int i = 0; i < b; ++i) base += pp[i];       // LDS-resident prefix (<= 97 adds)
    for (int d = 1; d < 256; d <<= 1){
        int v = (t >= d) ? sh[t-d] : 0;
        __syncthreads();
        sh[t] += v;
        __syncthreads();
    }
    int excl = base + sh[t] - (c0 + c1);
    if (i0 < MM){ offs[i0] = excl;      cursor[i0] = excl; }
    if (i0 + 1 < MM){ offs[i0+1] = excl + c0; cursor[i0+1] = excl + c0; }
    if (b == gridDim.x-1 && t == 255) offs[MM] = EE;
}

// edges stored as (col*1024 byte offset, bits(val)) — pre-shifted to cut spmm VALU
__global__ __launch_bounds__(256) void k_scatter(const int* __restrict__ rows, const int* __restrict__ cols,
                                                 const float* __restrict__ vals, int* __restrict__ cursor,
                                                 int2* __restrict__ edges){
    int e = blockIdx.x*256 + threadIdx.x;
    if (e >= EE) return;
    int r = rows[e];
    int pos = atomicAdd(&cursor[r], 1);
    edges[pos] = make_int2(cols[e] << 10, __float_as_int(vals[e]));
}

// ---- Full-width SpMM: Xout = alpha*(L@Xin) - (sub?Xprev:0) ----
// R8 lesson: sub-slab/XCD-pinning is a net loss (497 MB fetch, split cache
// lines across XCDs). Budget reconstruction shows the 12.8MB-slab version was
// ALSO slower than plain full-width (157 vs 123.5 us/pass). This is the
// full-width form, upgraded: ONE WAVE PER ROW, 16 B/lane (64 lanes = 1 KB =
// whole row per edge -> full 128-B lines, half the load instructions of the
// R1 8B/lane version), 4 independent 1 KB gathers in flight per wave, edge
// meta prefetched one burst ahead. Tail edges padded with val=0 and
// col=col[start] (cache-hot, no divergence). Per-column accumulation order is
// j-ascending — identical math to the verified R1 kernel.
__global__ __launch_bounds__(256) void k_spmm_w(const unsigned short* __restrict__ Xin,
                                                const unsigned short* __restrict__ Xprev,
                                                unsigned short* __restrict__ Xout,
                                                const int* __restrict__ offs,
                                                const int2* __restrict__ edges,
                                                float alpha, int sub){
    const int m    = blockIdx.x*4 + (threadIdx.x >> 6);   // grid 12500*4 = 50000 exact
    const int lane = threadIdx.x & 63;
    const int cb   = lane*16;                             // byte offset within 1024-B row
    const int start = offs[m], end = offs[m+1];

    float acc[8];
    #pragma unroll
    for (int d = 0; d < 8; ++d) acc[d] = 0.f;

    const char* __restrict__ bp = (const char*)Xin;
    const long long* __restrict__ ep = (const long long*)edges;

    if (start < end){
        const long long base = ep[start];                 // pad source (val ignored)
        const int basec = (int)base;
        int  c[4]; float v[4];
        {   // initial meta burst (padded)
            #pragma unroll
            for (int q = 0; q < 4; ++q){
                int je = start + q;
                bool ok = je < end;
                long long e = ok ? ep[je] : base;
                c[q] = ok ? (int)e : basec;
                v[q] = ok ? __int_as_float((int)(e >> 32)) : 0.f;
            }
        }
        int j = start;
        while (j < end){
            int cc[4]; float vv[4];
            #pragma unroll
            for (int q = 0; q < 4; ++q){ cc[q] = c[q]; vv[q] = v[q]; }
            j += 4;
            if (j < end){                                 // prefetch next meta burst
                #pragma unroll
                for (int q = 0; q < 4; ++q){
                    int je = j + q;
                    bool ok = je < end;
                    long long e = ok ? ep[je] : base;
                    c[q] = ok ? (int)e : basec;
                    v[q] = ok ? __int_as_float((int)(e >> 32)) : 0.f;
                }
            }
            uint4 x[4];                                   // 4 x 1KB gathers in flight
            #pragma unroll
            for (int q = 0; q < 4; ++q)
                x[q] = *(const uint4*)(bp + (unsigned)cc[q] + cb);
            #pragma unroll
            for (int q = 0; q < 4; ++q){
                const unsigned int* xw = (const unsigned int*)&x[q];
                #pragma unroll
                for (int d = 0; d < 4; ++d){
                    unsigned int u = xw[d];
                    union{unsigned int ui; float f;} lo, hi;
                    lo.ui = u << 16; hi.ui = u & 0xffff0000u;
                    acc[d*2]   += vv[q]*lo.f;
                    acc[d*2+1] += vv[q]*hi.f;
                }
            }
        }
    }

    #pragma unroll
    for (int d = 0; d < 8; ++d) acc[d] *= alpha;
    size_t ob = (size_t)m*1024 + cb;
    if (sub){
        uint4 pv = *(const uint4*)((const char*)Xprev + ob);
        const unsigned int* pw = (const unsigned int*)&pv;
        #pragma unroll
        for (int d = 0; d < 4; ++d){
            unsigned int u = pw[d];
            union{unsigned int ui; float f;} lo, hi;
            lo.ui = u << 16; hi.ui = u & 0xffff0000u;
            acc[d*2]   -= lo.f;
            acc[d*2+1] -= hi.f;
        }
    }
    unsigned int o[4];
    #pragma unroll
    for (int d = 0; d < 4; ++d)
        o[d] = ((unsigned int)f2bf(acc[d*2+1]) << 16) | (unsigned int)f2bf(acc[d*2]);
    *(uint4*)((char*)Xout + ob) = *(const uint4*)o;
}

// ---- GEMM: 256 rows x 128 cols per block, A+B staged via global_load_lds
// double-buffered LDS (BK=32, 16 k-steps). A-tile LDS uses XOR swizzle
// byte ^= ((row&6)<<3) applied on BOTH staging source and ds_read (G21). ----
__global__ __launch_bounds__(256, 2) void k_gemm(const unsigned short* __restrict__ X0,
                                                 const unsigned short* __restrict__ X1,
                                                 const unsigned short* __restrict__ X2,
                                                 const unsigned short* __restrict__ X3,
                                                 const unsigned short* __restrict__ Wt,
                                                 float* __restrict__ Y,
                                                 float* __restrict__ Ypart){
    const int wave = threadIdx.x >> 6;
    const int lane = threadIdx.x & 63;
    const int l16  = lane & 15;
    const int g    = lane >> 4;                       // 0..3
    const int bidx = blockIdx.y;                      // batch
    const int m0   = blockIdx.x*256;                  // row-tile base

    __shared__ unsigned short As[2][8192];            // 2 x 16 KB: 256 rows x 32 k (swizzled)
    __shared__ unsigned short Bs[2][4096];            // 2 x 8 KB: 128 cols x 32 k (frag order)

    const unsigned short* const Xs[4] = {X0, X1, X2, X3};

    f32x4 acc[4][8];
    #pragma unroll
    for (int i = 0; i < 4; ++i)
        #pragma unroll
        for (int j = 0; j < 8; ++j) acc[i][j] = (f32x4){0.f,0.f,0.f,0.f};

    auto stage = [&](int buf, int ks){
        const unsigned short* Xb = Xs[ks >> 2];
        const int f0 = (ks & 3)*64;                   // byte offset of 32-k slice in 256-B batch row
        #pragma unroll
        for (int q = 0; q < 4; ++q){                  // A: 16 KB
            int row = q*64 + wave*16 + (lane >> 2);
            int mr  = m0 + row; if (mr >= MM) mr = MM-1;
            int inner = ((lane & 3)*16) ^ ((row & 6) << 3);   // source pre-swizzle
            const char* src = (const char*)Xb + (size_t)mr*1024 + bidx*256 + f0 + inner;
            lds_uint* dst = (lds_uint*)(&As[buf][(q*4096 + wave*1024)/2]);
            __builtin_amdgcn_global_load_lds((gbl_uint*)src, dst, 16, 0, 0);
        }
        #pragma unroll
        for (int q = 0; q < 2; ++q){                  // B: 8 KB
            int ns = q*4 + wave;
            const char* src = (const char*)Wt + (size_t)(ns*16 + ks)*1024 + lane*16;
            lds_uint* dst = (lds_uint*)(&Bs[buf][ns*512]);
            __builtin_amdgcn_global_load_lds((gbl_uint*)src, dst, 16, 0, 0);
        }
    };

    stage(0, 0);
    __syncthreads();

    for (int ks = 0; ks < 16; ++ks){
        const int buf = ks & 1;
        if (ks < 15) stage(buf ^ 1, ks + 1);

        bf16x8 a[4];
        #pragma unroll
        for (int i = 0; i < 4; ++i){
            int rr = wave*64 + i*16 + l16;
            int phys = rr*64 + ((g*16) ^ ((rr & 6) << 3));    // matching read swizzle
            a[i] = *(const bf16x8*)((const char*)&As[buf][0] + phys);
        }
        #pragma unroll
        for (int ns = 0; ns < 8; ++ns){
            bf16x8 b = *(const bf16x8*)(&Bs[buf][ns*512 + lane*8]);
            #pragma unroll
            for (int i = 0; i < 4; ++i)
                acc[i][ns] = __builtin_amdgcn_mfma_f32_16x16x32_bf16(a[i], b, acc[i][ns], 0, 0, 0);
        }
        __syncthreads();
    }

    // epilogue: relu + store + per-block column partial sums
    __shared__ float ldsum[4][FOUTF];
    float csum[8];
    #pragma unroll
    for (int ns = 0; ns < 8; ++ns) csum[ns] = 0.f;

    #pragma unroll
    for (int i = 0; i < 4; ++i){
        #pragma unroll
        for (int reg = 0; reg < 4; ++reg){
            int mr = m0 + wave*64 + i*16 + g*4 + reg;
            if (mr < MM){
                #pragma unroll
                for (int ns = 0; ns < 8; ++ns){
                    float v = acc[i][ns][reg];
                    v = v > 0.f ? v : 0.f;
                    Y[((size_t)bidx*MM + mr)*FOUTF + ns*16 + l16] = v;
                    csum[ns] += v;
                }
            }
        }
    }
    #pragma unroll
    for (int ns = 0; ns < 8; ++ns){
        float v = csum[ns];
        v += __shfl_xor(v, 16);                       // sum over g = 0..3
        v += __shfl_xor(v, 32);
        csum[ns] = v;
    }
    if (lane < 16){
        #pragma unroll
        for (int ns = 0; ns < 8; ++ns) ldsum[wave][ns*16 + lane] = csum[ns];
    }
    __syncthreads();
    int t = threadIdx.x;
    if (t < FOUTF){
        float s = ldsum[0][t] + ldsum[1][t] + ldsum[2][t] + ldsum[3][t];
        Ypart[((size_t)bidx*GXB + blockIdx.x)*FOUTF + t] = s;
    }
}

// ---- SE MLP: reduce gemm partials -> mean -> u = sigmoid(swish(mean@Wd+bd)@Wu+bu) ----
__global__ __launch_bounds__(128) void k_se(const float* __restrict__ Ypart,
                                            const float* __restrict__ Wd, const float* __restrict__ bd,
                                            const float* __restrict__ Wu, const float* __restrict__ bu,
                                            float* __restrict__ u){
    int b = blockIdx.x, t = threadIdx.x;
    __shared__ float sm[128];
    __shared__ float dsh[16];
    float s = 0.f;
    for (int j = 0; j < GXB; ++j) s += Ypart[((size_t)b*GXB + j)*FOUTF + t];
    sm[t] = s * (1.0f/MM);
    __syncthreads();
    if (t < 16){
        float a = bd[t];
        for (int f = 0; f < 128; ++f) a += sm[f]*Wd[f*16 + t];
        dsh[t] = a / (1.f + expf(-a));                // swish
    }
    __syncthreads();
    float a = bu[t];
    for (int j = 0; j < 16; ++j) a += dsh[j]*Wu[j*FOUTF + t];
    u[b*FOUTF + t] = 1.f/(1.f + expf(-a));
}

// ---- out = Y * u[b] ----
__global__ __launch_bounds__(256) void k_scale(const float* __restrict__ Y, const float* __restrict__ u,
                                               float* __restrict__ out){
    int tid = blockIdx.x*256 + threadIdx.x;
    if (tid >= NROWS*FOUTF/4) return;
    int b  = tid / (MM*FOUTF/4);
    int f4 = tid & 31;
    float4 yv = ((const float4*)Y)[tid];
    float4 uv = *(const float4*)(u + b*FOUTF + f4*4);
    float4 o;
    o.x = yv.x*uv.x; o.y = yv.y*uv.y; o.z = yv.z*uv.z; o.w = yv.w*uv.w;
    ((float4*)out)[tid] = o;
}

extern "C" void kernel_launch(void* const* d_in, const int* in_sizes, int n_in,
                              void* d_out, int out_size, void* d_ws, size_t ws_size,
                              hipStream_t stream){
    (void)in_sizes; (void)n_in; (void)out_size; (void)ws_size;
    const float* x    = (const float*)d_in[0];
    const float* lv   = (const float*)d_in[1];
    const int*   lr   = (const int*)d_in[2];
    const int*   lc   = (const int*)d_in[3];
    const float* kern = (const float*)d_in[4];
    const float* Wd   = (const float*)d_in[5];
    const float* bd   = (const float*)d_in[6];
    const float* Wu   = (const float*)d_in[7];
    const float* bu   = (const float*)d_in[8];
    float* out = (float*)d_out;

    char* w = (char*)d_ws;
    size_t off = 0;
    auto take = [&](size_t bytes)->char*{
        char* p = w + off; off += (bytes + 255) & ~(size_t)255; return p;
    };
    unsigned short* X[4];
    for (int i = 0; i < 4; ++i) X[i] = (unsigned short*)take((size_t)MM*XC*2);
    float* Y           = (float*)take((size_t)NROWS*FOUTF*4);
    unsigned short* Wt = (unsigned short*)take((size_t)FOUTF*CD*2);
    int* counts        = (int*)take((size_t)MM*4);
    int* offs          = (int*)take((size_t)(MM+1)*4);
    int* cursor        = (int*)take((size_t)MM*4);
    int2* edges        = (int2*)take((size_t)EE*8);
    int* part          = (int*)take((size_t)NSB*4);
    float* Ypart       = (float*)take((size_t)BB*GXB*FOUTF*4);
    float* u           = (float*)take((size_t)BB*FOUTF*4);

    hipMemsetAsync(counts, 0, MM*4, stream);

    k_init_x0<<<25000, 256, 0, stream>>>(x, X[0]);
    k_prepw<<<256, 256, 0, stream>>>(kern, Wt);
    k_hist<<<(EE+255)/256, 256, 0, stream>>>(lr, counts);
    k_scanA<<<NSB, 256, 0, stream>>>(counts, part);
    k_scanC<<<NSB, 256, 0, stream>>>(counts, part, offs, cursor);
    k_scatter<<<(EE+255)/256, 256, 0, stream>>>(lr, lc, lv, cursor, edges);

    // Chebyshev recurrence: full-width passes, one wave per row
    k_spmm_w<<<MM/4, 256, 0, stream>>>(X[0], X[0], X[1], offs, edges, 1.0f, 0);
    k_spmm_w<<<MM/4, 256, 0, stream>>>(X[1], X[0], X[2], offs, edges, 2.0f, 1);
    k_spmm_w<<<MM/4, 256, 0, stream>>>(X[2], X[1], X[3], offs, edges, 2.0f, 1);

    dim3 ggemm(GXB, BB);
    k_gemm<<<ggemm, 256, 0, stream>>>(X[0], X[1], X[2], X[3], Wt, Y, Ypart);

    k_se<<<BB, 128, 0, stream>>>(Ypart, Wd, bd, Wu, bu, u);
    k_scale<<<25000, 256, 0, stream>>>(Y, u, out);
}